// Round 6
// baseline (964.697 us; speedup 1.0000x reference)
//
#include <hip/hip_runtime.h>
#include <hip/hip_cooperative_groups.h>
namespace cg = cooperative_groups;

#define NNODE 10000
#define NEDGE 160000
#define GRID  512
#define NTHR  256

using frag8 = __attribute__((ext_vector_type(8))) short;
using f32x4 = __attribute__((ext_vector_type(4))) float;

__device__ __forceinline__ unsigned short f2bf(float f) {
    union { float f; unsigned u; } v; v.f = f;
    unsigned r = (v.u + 0x7fffu + ((v.u >> 16) & 1u)) >> 16;
    return (unsigned short)r;
}
__device__ __forceinline__ float bf2f(unsigned short s) {
    union { unsigned u; float f; } v; v.u = ((unsigned)s) << 16; return v.f;
}

struct P {
    const float* x; const int* srcI; const int* dstI;
    const float *wl1, *wr1, *wl2, *wr2, *wl3, *wr3;
    const float *b1, *g1, *be1, *m1, *v1;
    const float *b2, *g2, *be2, *m2, *v2;
    const float *b3;
    int *deg, *rs, *cur, *csr;
    unsigned short *xb, *bt1, *bt2, *bt3, *agg, *h1, *h2;
    float *sc1, *sh1, *sc2, *sh2, *sc3, *sh3;
    float* out;
};

// ---------- aggregation phase: wave-jobs (node, pass), pass-major ----------
__device__ __forceinline__ void agg_phase(const unsigned short* __restrict__ S,
                                          const int* __restrict__ rs,
                                          const int* __restrict__ csr,
                                          unsigned short* __restrict__ outb) {
    const int lane = threadIdx.x & 63;
    const int wv = blockIdx.x * 4 + (threadIdx.x >> 6);
    for (int job = wv; job < 4 * NNODE; job += GRID * 4) {
        const int pass = job / NNODE;
        const int n = job - pass * NNODE;
        const int c = pass * 128 + lane * 2;
        const int s = rs[n], e = rs[n + 1];
        float a0 = 0.f, a1 = 0.f;
        int i = s;
        for (; i + 4 <= e; i += 4) {
            int r0 = csr[i], r1 = csr[i + 1], r2 = csr[i + 2], r3 = csr[i + 3];
            unsigned u0 = *(const unsigned*)(S + (long)r0 * 512 + c);
            unsigned u1 = *(const unsigned*)(S + (long)r1 * 512 + c);
            unsigned u2 = *(const unsigned*)(S + (long)r2 * 512 + c);
            unsigned u3 = *(const unsigned*)(S + (long)r3 * 512 + c);
            a0 += bf2f((unsigned short)(u0 & 0xffffu)); a1 += bf2f((unsigned short)(u0 >> 16));
            a0 += bf2f((unsigned short)(u1 & 0xffffu)); a1 += bf2f((unsigned short)(u1 >> 16));
            a0 += bf2f((unsigned short)(u2 & 0xffffu)); a1 += bf2f((unsigned short)(u2 >> 16));
            a0 += bf2f((unsigned short)(u3 & 0xffffu)); a1 += bf2f((unsigned short)(u3 >> 16));
        }
        for (; i < e; i++) {
            unsigned u = *(const unsigned*)(S + (long)csr[i] * 512 + c);
            a0 += bf2f((unsigned short)(u & 0xffffu)); a1 += bf2f((unsigned short)(u >> 16));
        }
        const int cnt = e - s;
        const float inv = 1.f / (float)(cnt > 1 ? cnt : 1);
        unsigned o = (unsigned)f2bf(a0 * inv) | ((unsigned)f2bf(a1 * inv) << 16);
        *(unsigned*)(outb + (long)n * 512 + c) = o;
    }
}

// ---------- GEMM phase: XCD-ownership decode + dbuf, virtual-block loop ----------
__device__ __forceinline__ void gemm_phase(const unsigned short* __restrict__ Agg,
                                           const unsigned short* __restrict__ Self,
                                           const unsigned short* __restrict__ Bt,
                                           const float* __restrict__ sc, const float* __restrict__ sh,
                                           unsigned short* __restrict__ hout, float* __restrict__ fout,
                                           int NT, int qsh, int mode,
                                           short* __restrict__ AsB, short* __restrict__ BsB) {
    const int tid = threadIdx.x;
    const int w = tid >> 6, lane = tid & 63;
    const int wm = (w >> 1) * 64, wn = (w & 1) * 32;
    const int fr = lane & 15, fq = lane >> 4, sw = fr & 7;
    const int srow = w * 8 + (lane >> 3);
    const int scol = (((lane & 7) ^ (lane >> 3)) * 8);
    const int ldsOff = w * 8 * 64;
    const int vtiles = 80 * NT;

    for (int vb = blockIdx.x; vb < vtiles; vb += GRID) {
        const int X = vb & 7;
        const int q = (vb >> 3) & (NT - 1);
        const int g = vb >> qsh;
        const int m0 = (g * 8 + X) * 128;
        if (m0 >= NNODE) continue;
        const int n0 = q * 64;

        f32x4 acc[4][2];
#pragma unroll
        for (int i = 0; i < 4; i++)
#pragma unroll
            for (int j = 0; j < 2; j++)
#pragma unroll
                for (int r = 0; r < 4; r++) acc[i][j][r] = 0.f;

        auto issue = [&](int t, int buf) {
            const short* abase = (const short*)((t < 8) ? Agg : Self);
            const int kk = (t & 7) * 64;
            const int k0 = t * 64;
            short* asD = AsB + buf * 128 * 64 + ldsOff;
            short* bsD = BsB + buf * 64 * 64 + ldsOff;
#pragma unroll
            for (int cch = 0; cch < 4; cch++)
                __builtin_amdgcn_global_load_lds(
                    (const __attribute__((address_space(1))) void*)(abase + (long)(m0 + cch * 32 + srow) * 512 + kk + scol),
                    (__attribute__((address_space(3))) void*)(asD + cch * 32 * 64), 16, 0, 0);
#pragma unroll
            for (int cch = 0; cch < 2; cch++)
                __builtin_amdgcn_global_load_lds(
                    (const __attribute__((address_space(1))) void*)((const short*)Bt + (long)(n0 + cch * 32 + srow) * 1024 + k0 + scol),
                    (__attribute__((address_space(3))) void*)(bsD + cch * 32 * 64), 16, 0, 0);
        };

        issue(0, 0);
#pragma unroll
        for (int t = 0; t < 16; t++) {
            const int cur = t & 1;
            __syncthreads();
            if (t < 15) issue(t + 1, cur ^ 1);
            const short* AsC = AsB + cur * 128 * 64;
            const short* BsC = BsB + cur * 64 * 64;
#pragma unroll
            for (int ks = 0; ks < 2; ks++) {
                frag8 af[4], bf[2];
#pragma unroll
                for (int i = 0; i < 4; i++)
                    af[i] = *(const frag8*)(AsC + (wm + i * 16 + fr) * 64 + (((ks * 4 + fq) ^ sw) * 8));
#pragma unroll
                for (int j = 0; j < 2; j++)
                    bf[j] = *(const frag8*)(BsC + (wn + j * 16 + fr) * 64 + (((ks * 4 + fq) ^ sw) * 8));
#pragma unroll
                for (int i = 0; i < 4; i++)
#pragma unroll
                    for (int j = 0; j < 2; j++)
                        acc[i][j] = __builtin_amdgcn_mfma_f32_16x16x32_bf16(af[i], bf[j], acc[i][j], 0, 0, 0);
            }
            __syncthreads();
        }

        float scj[2], shj[2];
#pragma unroll
        for (int j = 0; j < 2; j++) {
            int col = n0 + wn + j * 16 + fr;
            scj[j] = sc[col]; shj[j] = sh[col];
        }
        const int NOUT = NT * 64;
#pragma unroll
        for (int i = 0; i < 4; i++) {
            int rowb = m0 + wm + i * 16 + fq * 4;
#pragma unroll
            for (int j = 0; j < 2; j++) {
                int col = n0 + wn + j * 16 + fr;
#pragma unroll
                for (int r = 0; r < 4; r++) {
                    int row = rowb + r;
                    if (row < NNODE) {
                        float y = acc[i][j][r] * scj[j] + shj[j];
                        if (mode == 0) {
                            y = fmaxf(y, 0.f);
                            hout[(long)row * 512 + col] = f2bf(y);
                        } else {
                            fout[(long)row * NOUT + col] = y;
                        }
                    }
                }
            }
        }
    }
}

// ---------------- the mega-kernel ----------------
__global__ __launch_bounds__(NTHR, 2) void mega(P p) {
    __shared__ __align__(16) short As[2 * 128 * 64];   // 32 KB
    __shared__ __align__(16) short Bs[2 * 64 * 64];    // 16 KB
    __shared__ float tt[32][33];                       // 4.2 KB
    __shared__ int wt[4];
    cg::grid_group grid = cg::this_grid();
    const int b = blockIdx.x, tid = threadIdx.x;
    const int gt = b * NTHR + tid;

    // ---- Phase A: zero deg + x-cast + weight transposes + scale/shift ----
    if (gt < NNODE) p.deg[gt] = 0;
    for (int j = b; j < 5000; j += GRID) {           // x cast, 5000 float4-units of 256
        int i = j * 256 + tid;
        float4 f = ((const float4*)p.x)[i];
        ushort4 o;
        o.x = f2bf(f.x); o.y = f2bf(f.y); o.z = f2bf(f.z); o.w = f2bf(f.w);
        ((ushort4*)p.xb)[i] = o;
    }
    if (b == GRID - 1) {                             // scale/shift
        for (int t = tid; t < 512; t += NTHR) {
            float s1 = p.g1[t] * rsqrtf(p.v1[t] + 1e-5f);
            p.sc1[t] = s1; p.sh1[t] = (p.b1[t] - p.m1[t]) * s1 + p.be1[t];
            float s2 = p.g2[t] * rsqrtf(p.v2[t] + 1e-5f);
            p.sc2[t] = s2; p.sh2[t] = (p.b2[t] - p.m2[t]) * s2 + p.be2[t];
        }
        if (tid < 256) { p.sc3[tid] = 1.0f; p.sh3[tid] = p.b3[tid]; }
    }
    for (int tj = b; tj < 1280; tj += GRID) {        // transposes: bt[n*1024+koff+k] = w[k*C+n]
        const float* srcp; unsigned short* dstp; int C, koff, ntilesN, tl;
        if (tj < 1024) {
            int job = tj >> 8; tl = tj & 255; C = 512; ntilesN = 16;
            srcp = (job == 0) ? p.wl1 : (job == 1) ? p.wr1 : (job == 2) ? p.wl2 : p.wr2;
            dstp = (job < 2) ? p.bt1 : p.bt2; koff = (job & 1) * 512;
        } else {
            int jj = tj - 1024; int job = jj >> 7; tl = jj & 127; C = 256; ntilesN = 8;
            srcp = (job == 0) ? p.wl3 : p.wr3; dstp = p.bt3; koff = job * 512;
        }
        int k0 = (tl / ntilesN) * 32, c0 = (tl % ntilesN) * 32;
        int tx = tid & 31, ty = tid >> 5;
        __syncthreads();
#pragma unroll
        for (int q = 0; q < 4; q++)
            tt[ty + 8 * q][tx] = srcp[(long)(k0 + ty + 8 * q) * C + c0 + tx];
        __syncthreads();
#pragma unroll
        for (int q = 0; q < 4; q++)
            dstp[(long)(c0 + ty + 8 * q) * 1024 + koff + k0 + tx] = f2bf(tt[tx][ty + 8 * q]);
    }
    grid.sync();

    // ---- Phase B: degree count ----
    for (int e = gt; e < NEDGE; e += GRID * NTHR)
        atomicAdd(&p.deg[p.dstI[e]], 1);
    grid.sync();

    // ---- Phase C: scan (block 0 only) ----
    if (b == 0) {
        const int CH = 40;
        const int base = tid * CH;
        int tsum = 0;
        for (int j = 0; j < CH; j++) {
            int idx = base + j;
            tsum += (idx < NNODE) ? p.deg[idx] : 0;
        }
        const int lane = tid & 63, wid = tid >> 6;
        int xx = tsum;
#pragma unroll
        for (int d = 1; d < 64; d <<= 1) {
            int y = __shfl_up(xx, d, 64);
            if (lane >= d) xx += y;
        }
        if (lane == 63) wt[wid] = xx;
        __syncthreads();
        if (tid == 0) {
            int c = 0;
#pragma unroll
            for (int k = 0; k < 4; k++) { int t2 = wt[k]; wt[k] = c; c += t2; }
        }
        __syncthreads();
        int run = wt[wid] + xx - tsum;
        for (int j = 0; j < CH; j++) {
            int idx = base + j;
            if (idx < NNODE) {
                p.rs[idx] = run; p.cur[idx] = run;
                run += p.deg[idx];
            }
        }
        if (tid == 0) p.rs[NNODE] = NEDGE;
    }
    grid.sync();

    // ---- Phase D: CSR fill ----
    for (int e = gt; e < NEDGE; e += GRID * NTHR) {
        int pos = atomicAdd(&p.cur[p.dstI[e]], 1);
        p.csr[pos] = p.srcI[e];
    }
    grid.sync();

    // ---- Layer 1 ----
    agg_phase(p.xb, p.rs, p.csr, p.agg);
    grid.sync();
    gemm_phase(p.agg, p.xb, p.bt1, p.sc1, p.sh1, p.h1, nullptr, 8, 6, 0, As, Bs);
    grid.sync();
    // ---- Layer 2 ----
    agg_phase(p.h1, p.rs, p.csr, p.agg);
    grid.sync();
    gemm_phase(p.agg, p.h1, p.bt2, p.sc2, p.sh2, p.h2, nullptr, 8, 6, 0, As, Bs);
    grid.sync();
    // ---- Layer 3 ----
    agg_phase(p.h2, p.rs, p.csr, p.agg);
    grid.sync();
    gemm_phase(p.agg, p.h2, p.bt3, p.sc3, p.sh3, nullptr, p.out, 4, 5, 1, As, Bs);
}

extern "C" void kernel_launch(void* const* d_in, const int* in_sizes, int n_in,
                              void* d_out, int out_size, void* d_ws, size_t ws_size,
                              hipStream_t stream) {
    P p;
    p.x    = (const float*)d_in[0];
    const int* ei = (const int*)d_in[1];
    p.srcI = ei; p.dstI = ei + NEDGE;
    p.wl1 = (const float*)d_in[2];  p.b1 = (const float*)d_in[3];  p.wr1 = (const float*)d_in[4];
    p.g1 = (const float*)d_in[5];   p.be1 = (const float*)d_in[6];
    p.m1 = (const float*)d_in[7];   p.v1 = (const float*)d_in[8];
    p.wl2 = (const float*)d_in[9];  p.b2 = (const float*)d_in[10]; p.wr2 = (const float*)d_in[11];
    p.g2 = (const float*)d_in[12];  p.be2 = (const float*)d_in[13];
    p.m2 = (const float*)d_in[14];  p.v2 = (const float*)d_in[15];
    p.wl3 = (const float*)d_in[16]; p.b3 = (const float*)d_in[17]; p.wr3 = (const float*)d_in[18];
    p.out = (float*)d_out;

    char* w = (char*)d_ws;
    auto alloc = [&](size_t bytes) { void* q = (void*)w; w += (bytes + 255) & ~(size_t)255; return q; };
    p.deg = (int*)alloc((size_t)NNODE * 4);
    p.rs  = (int*)alloc((size_t)(NNODE + 1) * 4);
    p.cur = (int*)alloc((size_t)NNODE * 4);
    p.csr = (int*)alloc((size_t)NEDGE * 4);
    p.xb  = (unsigned short*)alloc((size_t)NNODE * 512 * 2);
    p.bt1 = (unsigned short*)alloc((size_t)512 * 1024 * 2);
    p.bt2 = (unsigned short*)alloc((size_t)512 * 1024 * 2);
    p.bt3 = (unsigned short*)alloc((size_t)256 * 1024 * 2);
    p.sc1 = (float*)alloc(512 * 4); p.sh1 = (float*)alloc(512 * 4);
    p.sc2 = (float*)alloc(512 * 4); p.sh2 = (float*)alloc(512 * 4);
    p.sc3 = (float*)alloc(256 * 4); p.sh3 = (float*)alloc(256 * 4);
    p.agg = (unsigned short*)alloc((size_t)NNODE * 512 * 2);
    p.h1  = (unsigned short*)alloc((size_t)NNODE * 512 * 2);
    p.h2  = (unsigned short*)alloc((size_t)NNODE * 512 * 2);
    (void)alloc(256 * 1024);  // DMA over-read slack for last M-tile

    void* args[] = { &p };
    hipLaunchCooperativeKernel(reinterpret_cast<void*>(mega), dim3(GRID), dim3(NTHR),
                               args, 0, stream);
}

// Round 7
// 327.746 us; speedup vs baseline: 2.9434x; 2.9434x over previous
//
#include <hip/hip_runtime.h>

#define NNODE 10000
#define NEDGE 160000

using frag8 = __attribute__((ext_vector_type(8))) short;
using f32x4 = __attribute__((ext_vector_type(4))) float;

__device__ __forceinline__ unsigned short f2bf(float f) {
    union { float f; unsigned u; } v; v.f = f;
    unsigned r = (v.u + 0x7fffu + ((v.u >> 16) & 1u)) >> 16;
    return (unsigned short)r;
}
__device__ __forceinline__ float bf2f(unsigned short s) {
    union { unsigned u; float f; } v; v.u = ((unsigned)s) << 16; return v.f;
}

// ---------------- scan ----------------
__global__ __launch_bounds__(1024) void k_scan(const int* __restrict__ deg,
                                               int* __restrict__ rs,
                                               int* __restrict__ cur, int n, int total) {
    const int tid = threadIdx.x;
    const int CH = 10;
    const int base = tid * CH;
    int vals[CH];
    int tsum = 0;
#pragma unroll
    for (int j = 0; j < CH; j++) {
        int v = (base + j < n) ? deg[base + j] : 0;
        vals[j] = v; tsum += v;
    }
    const int lane = tid & 63, wid = tid >> 6;
    int x = tsum;
#pragma unroll
    for (int d = 1; d < 64; d <<= 1) {
        int y = __shfl_up(x, d, 64);
        if (lane >= d) x += y;
    }
    __shared__ int wt[16];
    if (lane == 63) wt[wid] = x;
    __syncthreads();
    if (tid == 0) {
        int c = 0;
#pragma unroll
        for (int k = 0; k < 16; k++) { int t = wt[k]; wt[k] = c; c += t; }
    }
    __syncthreads();
    int run = wt[wid] + x - tsum;
#pragma unroll
    for (int j = 0; j < CH; j++) {
        if (base + j < n) { rs[base + j] = run; cur[base + j] = run; }
        run += vals[j];
    }
    if (tid == 0) rs[n] = total;
}

__global__ void k_fill(const int* __restrict__ src, const int* __restrict__ dst,
                       int E, int* __restrict__ cur, int* __restrict__ csr) {
    int e = blockIdx.x * 256 + threadIdx.x;
    if (e < E) {
        int p = atomicAdd(&cur[dst[e]], 1);
        csr[p] = src[e];
    }
}

// ---------------- fused prep: x-cast + weight transposes + scale/shift + edge count ----------------
__global__ __launch_bounds__(256) void k_prep(
    const float* __restrict__ x, unsigned short* __restrict__ xb,
    const float* __restrict__ wl1, const float* __restrict__ wr1,
    const float* __restrict__ wl2, const float* __restrict__ wr2,
    const float* __restrict__ wl3, const float* __restrict__ wr3,
    unsigned short* __restrict__ bt1, unsigned short* __restrict__ bt2,
    unsigned short* __restrict__ bt3,
    const float* __restrict__ b1, const float* __restrict__ g1, const float* __restrict__ be1,
    const float* __restrict__ m1, const float* __restrict__ v1,
    const float* __restrict__ b2, const float* __restrict__ g2, const float* __restrict__ be2,
    const float* __restrict__ m2, const float* __restrict__ v2,
    const float* __restrict__ b3,
    float* __restrict__ sc1, float* __restrict__ sh1,
    float* __restrict__ sc2, float* __restrict__ sh2,
    float* __restrict__ sc3, float* __restrict__ sh3,
    const int* __restrict__ dstI, int* __restrict__ deg) {
    const int b = blockIdx.x, tid = threadIdx.x;
    if (b < 5000) {                       // x cast
        int i = b * 256 + tid;
        float4 f = ((const float4*)x)[i];
        ushort4 o;
        o.x = f2bf(f.x); o.y = f2bf(f.y); o.z = f2bf(f.z); o.w = f2bf(f.w);
        ((ushort4*)xb)[i] = o;
        return;
    }
    if (b >= 6281) {                      // edge degree count
        int e = (b - 6281) * 256 + tid;
        if (e < NEDGE) atomicAdd(&deg[dstI[e]], 1);
        return;
    }
    if (b == 6280) {                      // scale/shift
        for (int t = tid; t < 512; t += 256) {
            float s1 = g1[t] * rsqrtf(v1[t] + 1e-5f);
            sc1[t] = s1; sh1[t] = (b1[t] - m1[t]) * s1 + be1[t];
            float s2 = g2[t] * rsqrtf(v2[t] + 1e-5f);
            sc2[t] = s2; sh2[t] = (b2[t] - m2[t]) * s2 + be2[t];
        }
        if (tid < 256) { sc3[tid] = 1.0f; sh3[tid] = b3[tid]; }
        return;
    }
    __shared__ float t[32][33];
    int tj = b - 5000;
    const float* srcp; unsigned short* dstp; int C, koff, ntilesN;
    if (tj < 1024) {
        int job = tj >> 8; int tile = tj & 255; C = 512; ntilesN = 16;
        srcp = (job == 0) ? wl1 : (job == 1) ? wr1 : (job == 2) ? wl2 : wr2;
        dstp = (job < 2) ? bt1 : bt2; koff = (job & 1) * 512;
        tj = tile;
    } else {
        int jj = tj - 1024; int job = jj >> 7; int tile = jj & 127; C = 256; ntilesN = 8;
        srcp = (job == 0) ? wl3 : wr3; dstp = bt3; koff = job * 512;
        tj = tile;
    }
    int k0 = (tj / ntilesN) * 32, c0 = (tj % ntilesN) * 32;
    int tx = tid & 31, ty = tid >> 5;
#pragma unroll
    for (int q = 0; q < 4; q++)
        t[ty + 8 * q][tx] = srcp[(long)(k0 + ty + 8 * q) * C + c0 + tx];
    __syncthreads();
#pragma unroll
    for (int q = 0; q < 4; q++)
        dstp[(long)(c0 + ty + 8 * q) * 1024 + koff + k0 + tx] = f2bf(t[tx][ty + 8 * q]);
}

// ---------------- aggregation: 2 column passes (256 cols, 2.56MB slice/XCD-L2), uint2 loads ----------------
__global__ __launch_bounds__(64) void k_agg(const unsigned short* __restrict__ S,
                                            const int* __restrict__ rs, const int* __restrict__ csr,
                                            unsigned short* __restrict__ outb) {
    const int n = blockIdx.x;
    const int c = blockIdx.y * 256 + threadIdx.x * 4;
    const int s = rs[n], e = rs[n + 1];
    float a0 = 0.f, a1 = 0.f, a2 = 0.f, a3 = 0.f;
    int i = s;
    for (; i + 4 <= e; i += 4) {
        int r0 = csr[i], r1 = csr[i + 1], r2 = csr[i + 2], r3 = csr[i + 3];
        uint2 u0 = *(const uint2*)(S + (long)r0 * 512 + c);
        uint2 u1 = *(const uint2*)(S + (long)r1 * 512 + c);
        uint2 u2 = *(const uint2*)(S + (long)r2 * 512 + c);
        uint2 u3 = *(const uint2*)(S + (long)r3 * 512 + c);
        a0 += bf2f((unsigned short)(u0.x & 0xffffu)); a1 += bf2f((unsigned short)(u0.x >> 16));
        a2 += bf2f((unsigned short)(u0.y & 0xffffu)); a3 += bf2f((unsigned short)(u0.y >> 16));
        a0 += bf2f((unsigned short)(u1.x & 0xffffu)); a1 += bf2f((unsigned short)(u1.x >> 16));
        a2 += bf2f((unsigned short)(u1.y & 0xffffu)); a3 += bf2f((unsigned short)(u1.y >> 16));
        a0 += bf2f((unsigned short)(u2.x & 0xffffu)); a1 += bf2f((unsigned short)(u2.x >> 16));
        a2 += bf2f((unsigned short)(u2.y & 0xffffu)); a3 += bf2f((unsigned short)(u2.y >> 16));
        a0 += bf2f((unsigned short)(u3.x & 0xffffu)); a1 += bf2f((unsigned short)(u3.x >> 16));
        a2 += bf2f((unsigned short)(u3.y & 0xffffu)); a3 += bf2f((unsigned short)(u3.y >> 16));
    }
    for (; i < e; i++) {
        uint2 u = *(const uint2*)(S + (long)csr[i] * 512 + c);
        a0 += bf2f((unsigned short)(u.x & 0xffffu)); a1 += bf2f((unsigned short)(u.x >> 16));
        a2 += bf2f((unsigned short)(u.y & 0xffffu)); a3 += bf2f((unsigned short)(u.y >> 16));
    }
    const int cnt = e - s;
    const float inv = 1.f / (float)(cnt > 1 ? cnt : 1);
    uint2 o;
    o.x = (unsigned)f2bf(a0 * inv) | ((unsigned)f2bf(a1 * inv) << 16);
    o.y = (unsigned)f2bf(a2 * inv) | ((unsigned)f2bf(a3 * inv) << 16);
    *(uint2*)(outb + (long)n * 512 + c) = o;
}

// ---------------- GEMM: A-frags direct from L2, B via LDS dbuf (1 barrier/k0), XCD swizzle ----------------
// C[M x NOUT] = [Agg|Self][M x 1024] @ Bt[NOUT x 1024]^T, 128x64 tile, BK=64.
// MODE 0: relu(dot*sc+sh) -> bf16 stride 512 ; MODE 1: dot*sc+sh -> fp32 stride NOUT.
template <int MODE, int NOUT>
__global__ __launch_bounds__(256, 4) void k_gemm(const unsigned short* __restrict__ Agg,
                                                 const unsigned short* __restrict__ Self,
                                                 const unsigned short* __restrict__ Bt,
                                                 const float* __restrict__ sc, const float* __restrict__ sh,
                                                 unsigned short* __restrict__ hout, float* __restrict__ fout,
                                                 int M) {
    constexpr int NT = NOUT / 64;
    constexpr int QSH = (NT == 8) ? 6 : 5;
    const int b = blockIdx.x;
    const int X = b & 7;
    const int q = (b >> 3) & (NT - 1);
    const int g = b >> QSH;
    const int m0 = (g * 8 + X) * 128;
    if (m0 >= M) return;
    const int n0 = q * 64;

    __shared__ __align__(16) short Bs[2][64 * 64];    // 16 KB total
    const int tid = threadIdx.x;
    const int w = tid >> 6, lane = tid & 63;
    const int wm = (w >> 1) * 64, wn = (w & 1) * 32;
    const int fr = lane & 15, fq = lane >> 4, sw = fr & 7;
    const int srow = w * 8 + (lane >> 3);
    const int scol = (((lane & 7) ^ (lane >> 3)) * 8);
    const int ldsOff = w * 8 * 64;

    // A row offsets (in shorts) for this lane's 4 m-fragments
    long aoff[4];
#pragma unroll
    for (int i = 0; i < 4; i++)
        aoff[i] = (long)(m0 + wm + i * 16 + fr) * 512 + fq * 8;

    f32x4 acc[4][2];
#pragma unroll
    for (int i = 0; i < 4; i++)
#pragma unroll
        for (int j = 0; j < 2; j++)
#pragma unroll
            for (int r = 0; r < 4; r++) acc[i][j][r] = 0.f;

    auto issueB = [&](int t, int buf) {
        const int k0 = t * 64;
#pragma unroll
        for (int cch = 0; cch < 2; cch++)
            __builtin_amdgcn_global_load_lds(
                (const __attribute__((address_space(1))) void*)((const short*)Bt + (long)(n0 + cch * 32 + srow) * 1024 + k0 + scol),
                (__attribute__((address_space(3))) void*)(&Bs[buf][ldsOff + cch * 32 * 64]), 16, 0, 0);
    };

    issueB(0, 0);
#pragma unroll
    for (int t = 0; t < 16; t++) {
        const int cur = t & 1;
        const short* abase = (const short*)((t < 8) ? Agg : Self);
        const int kk = (t & 7) * 64;
        __syncthreads();                  // drains B-DMA(t); prior reads of buf cur^1 finished last iter
        if (t < 15) issueB(t + 1, cur ^ 1);
        frag8 af[2][4];
#pragma unroll
        for (int ks = 0; ks < 2; ks++)
#pragma unroll
            for (int i = 0; i < 4; i++)
                af[ks][i] = *(const frag8*)(abase + aoff[i] + kk + ks * 32);
#pragma unroll
        for (int ks = 0; ks < 2; ks++) {
            frag8 bf[2];
#pragma unroll
            for (int j = 0; j < 2; j++)
                bf[j] = *(const frag8*)(&Bs[cur][(wn + j * 16 + fr) * 64 + (((ks * 4 + fq) ^ sw) * 8)]);
#pragma unroll
            for (int i = 0; i < 4; i++)
#pragma unroll
                for (int j = 0; j < 2; j++)
                    acc[i][j] = __builtin_amdgcn_mfma_f32_16x16x32_bf16(af[ks][i], bf[j], acc[i][j], 0, 0, 0);
        }
    }

    float scj[2], shj[2];
#pragma unroll
    for (int j = 0; j < 2; j++) {
        int col = n0 + wn + j * 16 + fr;
        scj[j] = sc[col]; shj[j] = sh[col];
    }
#pragma unroll
    for (int i = 0; i < 4; i++) {
        int rowb = m0 + wm + i * 16 + fq * 4;
#pragma unroll
        for (int j = 0; j < 2; j++) {
            int col = n0 + wn + j * 16 + fr;
#pragma unroll
            for (int r = 0; r < 4; r++) {
                int row = rowb + r;
                if (row < M) {
                    float y = acc[i][j][r] * scj[j] + shj[j];
                    if constexpr (MODE == 0) {
                        y = fmaxf(y, 0.f);
                        hout[(long)row * 512 + col] = f2bf(y);
                    } else {
                        fout[(long)row * NOUT + col] = y;
                    }
                }
            }
        }
    }
}

extern "C" void kernel_launch(void* const* d_in, const int* in_sizes, int n_in,
                              void* d_out, int out_size, void* d_ws, size_t ws_size,
                              hipStream_t stream) {
    const float* x    = (const float*)d_in[0];
    const int*   ei   = (const int*)d_in[1];
    const float* w_l1 = (const float*)d_in[2];
    const float* b1   = (const float*)d_in[3];
    const float* w_r1 = (const float*)d_in[4];
    const float* g1   = (const float*)d_in[5];
    const float* be1  = (const float*)d_in[6];
    const float* m1   = (const float*)d_in[7];
    const float* v1   = (const float*)d_in[8];
    const float* w_l2 = (const float*)d_in[9];
    const float* b2   = (const float*)d_in[10];
    const float* w_r2 = (const float*)d_in[11];
    const float* g2   = (const float*)d_in[12];
    const float* be2  = (const float*)d_in[13];
    const float* m2   = (const float*)d_in[14];
    const float* v2   = (const float*)d_in[15];
    const float* w_l3 = (const float*)d_in[16];
    const float* b3   = (const float*)d_in[17];
    const float* w_r3 = (const float*)d_in[18];
    float* out = (float*)d_out;

    const int N = NNODE, E = NEDGE;
    const int* srcI = ei;
    const int* dstI = ei + E;

    char* w = (char*)d_ws;
    auto alloc = [&](size_t bytes) { void* p = (void*)w; w += (bytes + 255) & ~(size_t)255; return p; };
    int* deg = (int*)alloc((size_t)N * 4);
    int* rs  = (int*)alloc((size_t)(N + 1) * 4);
    int* cur = (int*)alloc((size_t)N * 4);
    int* csr = (int*)alloc((size_t)E * 4);
    unsigned short* xb   = (unsigned short*)alloc((size_t)N * 512 * 2);
    unsigned short* bt1  = (unsigned short*)alloc((size_t)512 * 1024 * 2);
    unsigned short* bt2  = (unsigned short*)alloc((size_t)512 * 1024 * 2);
    unsigned short* bt3  = (unsigned short*)alloc((size_t)256 * 1024 * 2);
    float* sc1 = (float*)alloc(512 * 4); float* sh1 = (float*)alloc(512 * 4);
    float* sc2 = (float*)alloc(512 * 4); float* sh2 = (float*)alloc(512 * 4);
    float* sc3 = (float*)alloc(256 * 4); float* sh3 = (float*)alloc(256 * 4);
    unsigned short* agg_a = (unsigned short*)alloc((size_t)N * 512 * 2);
    unsigned short* h1    = (unsigned short*)alloc((size_t)N * 512 * 2);
    unsigned short* h2    = (unsigned short*)alloc((size_t)N * 512 * 2);
    (void)alloc(256 * 1024);  // slack: last M-tile A-frag reads overrun ~114KB past buffers

    hipMemsetAsync(deg, 0, (size_t)N * 4, stream);
    k_prep<<<6906, 256, 0, stream>>>(x, xb, w_l1, w_r1, w_l2, w_r2, w_l3, w_r3,
                                     bt1, bt2, bt3,
                                     b1, g1, be1, m1, v1, b2, g2, be2, m2, v2, b3,
                                     sc1, sh1, sc2, sh2, sc3, sh3, dstI, deg);
    k_scan<<<1, 1024, 0, stream>>>(deg, rs, cur, N, E);
    k_fill<<<(E + 255) / 256, 256, 0, stream>>>(srcI, dstI, E, cur, csr);

    dim3 ga(N, 2);

    // Layer 1
    k_agg<<<ga, 64, 0, stream>>>(xb, rs, csr, agg_a);
    k_gemm<0, 512><<<640, 256, 0, stream>>>(agg_a, xb, bt1, sc1, sh1, h1, nullptr, N);
    // Layer 2
    k_agg<<<ga, 64, 0, stream>>>(h1, rs, csr, agg_a);
    k_gemm<0, 512><<<640, 256, 0, stream>>>(agg_a, h1, bt2, sc2, sh2, h2, nullptr, N);
    // Layer 3
    k_agg<<<ga, 64, 0, stream>>>(h2, rs, csr, agg_a);
    k_gemm<1, 256><<<320, 256, 0, stream>>>(agg_a, h2, bt3, sc3, sh3, nullptr, out, N);
}

// Round 8
// 249.558 us; speedup vs baseline: 3.8656x; 1.3133x over previous
//
#include <hip/hip_runtime.h>

#define NNODE 10000
#define NEDGE 160000

using frag8 = __attribute__((ext_vector_type(8))) short;
using f32x4 = __attribute__((ext_vector_type(4))) float;

__device__ __forceinline__ unsigned short f2bf(float f) {
    union { float f; unsigned u; } v; v.f = f;
    unsigned r = (v.u + 0x7fffu + ((v.u >> 16) & 1u)) >> 16;
    return (unsigned short)r;
}
__device__ __forceinline__ float bf2f(unsigned short s) {
    union { unsigned u; float f; } v; v.u = ((unsigned)s) << 16; return v.f;
}

// ---------------- scan ----------------
__global__ __launch_bounds__(1024) void k_scan(const int* __restrict__ deg,
                                               int* __restrict__ rs,
                                               int* __restrict__ cur, int n, int total) {
    const int tid = threadIdx.x;
    const int CH = 10;
    const int base = tid * CH;
    int vals[CH];
    int tsum = 0;
#pragma unroll
    for (int j = 0; j < CH; j++) {
        int v = (base + j < n) ? deg[base + j] : 0;
        vals[j] = v; tsum += v;
    }
    const int lane = tid & 63, wid = tid >> 6;
    int x = tsum;
#pragma unroll
    for (int d = 1; d < 64; d <<= 1) {
        int y = __shfl_up(x, d, 64);
        if (lane >= d) x += y;
    }
    __shared__ int wt[16];
    if (lane == 63) wt[wid] = x;
    __syncthreads();
    if (tid == 0) {
        int c = 0;
#pragma unroll
        for (int k = 0; k < 16; k++) { int t = wt[k]; wt[k] = c; c += t; }
    }
    __syncthreads();
    int run = wt[wid] + x - tsum;
#pragma unroll
    for (int j = 0; j < CH; j++) {
        if (base + j < n) { rs[base + j] = run; cur[base + j] = run; }
        run += vals[j];
    }
    if (tid == 0) rs[n] = total;
}

__global__ void k_fill(const int* __restrict__ src, const int* __restrict__ dst,
                       int E, int* __restrict__ cur, int* __restrict__ csr) {
    int e = blockIdx.x * 256 + threadIdx.x;
    if (e < E) {
        int p = atomicAdd(&cur[dst[e]], 1);
        csr[p] = src[e];
    }
}

// ---------------- fused prep: x-cast + weight transposes + scale/shift + edge count ----------------
__global__ __launch_bounds__(256) void k_prep(
    const float* __restrict__ x, unsigned short* __restrict__ xb,
    const float* __restrict__ wl1, const float* __restrict__ wr1,
    const float* __restrict__ wl2, const float* __restrict__ wr2,
    const float* __restrict__ wl3, const float* __restrict__ wr3,
    unsigned short* __restrict__ bt1, unsigned short* __restrict__ bt2,
    unsigned short* __restrict__ bt3,
    const float* __restrict__ b1, const float* __restrict__ g1, const float* __restrict__ be1,
    const float* __restrict__ m1, const float* __restrict__ v1,
    const float* __restrict__ b2, const float* __restrict__ g2, const float* __restrict__ be2,
    const float* __restrict__ m2, const float* __restrict__ v2,
    const float* __restrict__ b3,
    float* __restrict__ sc1, float* __restrict__ sh1,
    float* __restrict__ sc2, float* __restrict__ sh2,
    float* __restrict__ sc3, float* __restrict__ sh3,
    const int* __restrict__ dstI, int* __restrict__ deg) {
    const int b = blockIdx.x, tid = threadIdx.x;
    if (b < 5000) {                       // x cast
        int i = b * 256 + tid;
        float4 f = ((const float4*)x)[i];
        ushort4 o;
        o.x = f2bf(f.x); o.y = f2bf(f.y); o.z = f2bf(f.z); o.w = f2bf(f.w);
        ((ushort4*)xb)[i] = o;
        return;
    }
    if (b >= 6281) {                      // edge degree count
        int e = (b - 6281) * 256 + tid;
        if (e < NEDGE) atomicAdd(&deg[dstI[e]], 1);
        return;
    }
    if (b == 6280) {                      // scale/shift
        for (int t = tid; t < 512; t += 256) {
            float s1 = g1[t] * rsqrtf(v1[t] + 1e-5f);
            sc1[t] = s1; sh1[t] = (b1[t] - m1[t]) * s1 + be1[t];
            float s2 = g2[t] * rsqrtf(v2[t] + 1e-5f);
            sc2[t] = s2; sh2[t] = (b2[t] - m2[t]) * s2 + be2[t];
        }
        if (tid < 256) { sc3[tid] = 1.0f; sh3[tid] = b3[tid]; }
        return;
    }
    __shared__ float t[32][33];
    int tj = b - 5000;
    const float* srcp; unsigned short* dstp; int C, koff, ntilesN;
    if (tj < 1024) {
        int job = tj >> 8; int tile = tj & 255; C = 512; ntilesN = 16;
        srcp = (job == 0) ? wl1 : (job == 1) ? wr1 : (job == 2) ? wl2 : wr2;
        dstp = (job < 2) ? bt1 : bt2; koff = (job & 1) * 512;
        tj = tile;
    } else {
        int jj = tj - 1024; int job = jj >> 7; int tile = jj & 127; C = 256; ntilesN = 8;
        srcp = (job == 0) ? wl3 : wr3; dstp = bt3; koff = job * 512;
        tj = tile;
    }
    int k0 = (tj / ntilesN) * 32, c0 = (tj % ntilesN) * 32;
    int tx = tid & 31, ty = tid >> 5;
#pragma unroll
    for (int q = 0; q < 4; q++)
        t[ty + 8 * q][tx] = srcp[(long)(k0 + ty + 8 * q) * C + c0 + tx];
    __syncthreads();
#pragma unroll
    for (int q = 0; q < 4; q++)
        dstp[(long)(c0 + ty + 8 * q) * 1024 + koff + k0 + tx] = f2bf(t[tx][ty + 8 * q]);
}

// ---------------- aggregation: 2 column passes (256 cols/pass), uint2 loads ----------------
__global__ __launch_bounds__(64) void k_agg(const unsigned short* __restrict__ S,
                                            const int* __restrict__ rs, const int* __restrict__ csr,
                                            unsigned short* __restrict__ outb) {
    const int n = blockIdx.x;
    const int c = blockIdx.y * 256 + threadIdx.x * 4;
    const int s = rs[n], e = rs[n + 1];
    float a0 = 0.f, a1 = 0.f, a2 = 0.f, a3 = 0.f;
    int i = s;
    for (; i + 4 <= e; i += 4) {
        int r0 = csr[i], r1 = csr[i + 1], r2 = csr[i + 2], r3 = csr[i + 3];
        uint2 u0 = *(const uint2*)(S + (long)r0 * 512 + c);
        uint2 u1 = *(const uint2*)(S + (long)r1 * 512 + c);
        uint2 u2 = *(const uint2*)(S + (long)r2 * 512 + c);
        uint2 u3 = *(const uint2*)(S + (long)r3 * 512 + c);
        a0 += bf2f((unsigned short)(u0.x & 0xffffu)); a1 += bf2f((unsigned short)(u0.x >> 16));
        a2 += bf2f((unsigned short)(u0.y & 0xffffu)); a3 += bf2f((unsigned short)(u0.y >> 16));
        a0 += bf2f((unsigned short)(u1.x & 0xffffu)); a1 += bf2f((unsigned short)(u1.x >> 16));
        a2 += bf2f((unsigned short)(u1.y & 0xffffu)); a3 += bf2f((unsigned short)(u1.y >> 16));
        a0 += bf2f((unsigned short)(u2.x & 0xffffu)); a1 += bf2f((unsigned short)(u2.x >> 16));
        a2 += bf2f((unsigned short)(u2.y & 0xffffu)); a3 += bf2f((unsigned short)(u2.y >> 16));
        a0 += bf2f((unsigned short)(u3.x & 0xffffu)); a1 += bf2f((unsigned short)(u3.x >> 16));
        a2 += bf2f((unsigned short)(u3.y & 0xffffu)); a3 += bf2f((unsigned short)(u3.y >> 16));
    }
    for (; i < e; i++) {
        uint2 u = *(const uint2*)(S + (long)csr[i] * 512 + c);
        a0 += bf2f((unsigned short)(u.x & 0xffffu)); a1 += bf2f((unsigned short)(u.x >> 16));
        a2 += bf2f((unsigned short)(u.y & 0xffffu)); a3 += bf2f((unsigned short)(u.y >> 16));
    }
    const int cnt = e - s;
    const float inv = 1.f / (float)(cnt > 1 ? cnt : 1);
    uint2 o;
    o.x = (unsigned)f2bf(a0 * inv) | ((unsigned)f2bf(a1 * inv) << 16);
    o.y = (unsigned)f2bf(a2 * inv) | ((unsigned)f2bf(a3 * inv) << 16);
    *(uint2*)(outb + (long)n * 512 + c) = o;
}

// ---------------- GEMM: 128x128 tile, 4x4 frags/wave, LDS dbuf (1 barrier/iter), XCD swizzle ----------------
// C[M x NOUT] = [Agg|Self][M x 1024] @ Bt[NOUT x 1024]^T, BK=64.
// MODE 0: relu(dot*sc+sh) -> bf16 stride 512 ; MODE 1: dot*sc+sh -> fp32 stride NOUT.
template <int MODE, int NOUT>
__global__ __launch_bounds__(256, 2) void k_gemm(const unsigned short* __restrict__ Agg,
                                                 const unsigned short* __restrict__ Self,
                                                 const unsigned short* __restrict__ Bt,
                                                 const float* __restrict__ sc, const float* __restrict__ sh,
                                                 unsigned short* __restrict__ hout, float* __restrict__ fout,
                                                 int M) {
    constexpr int NT = NOUT / 128;          // n-tiles: 4 or 2
    constexpr int QSH = (NT == 4) ? 5 : 4;  // 3 + log2(NT)
    const int b = blockIdx.x;
    const int X = b & 7;
    const int q = (b >> 3) & (NT - 1);
    const int g = b >> QSH;
    const int m0 = (g * 8 + X) * 128;
    if (m0 >= M) return;
    const int n0 = q * 128;

    __shared__ __align__(16) short As[2][128 * 64];   // 32 KB
    __shared__ __align__(16) short Bs[2][128 * 64];   // 32 KB
    const int tid = threadIdx.x;
    const int w = tid >> 6, lane = tid & 63;
    const int wm = (w >> 1) * 64, wn = (w & 1) * 64;
    const int fr = lane & 15, fq = lane >> 4, sw = fr & 7;
    const int srow = w * 8 + (lane >> 3);                 // 0..31 (+chunk*32)
    const int scol = (((lane & 7) ^ (lane >> 3)) * 8);    // XOR-swizzled source col (shorts)
    const int ldsOff = w * 8 * 64;

    f32x4 acc[4][4];
#pragma unroll
    for (int i = 0; i < 4; i++)
#pragma unroll
        for (int j = 0; j < 4; j++)
#pragma unroll
            for (int r = 0; r < 4; r++) acc[i][j][r] = 0.f;

    auto issue = [&](int t, int buf) {
        const short* abase = (const short*)((t < 8) ? Agg : Self);
        const int kk = (t & 7) * 64;
        const int k0 = t * 64;
#pragma unroll
        for (int cch = 0; cch < 4; cch++) {
            __builtin_amdgcn_global_load_lds(
                (const __attribute__((address_space(1))) void*)(abase + (long)(m0 + cch * 32 + srow) * 512 + kk + scol),
                (__attribute__((address_space(3))) void*)(&As[buf][ldsOff + cch * 32 * 64]), 16, 0, 0);
            __builtin_amdgcn_global_load_lds(
                (const __attribute__((address_space(1))) void*)((const short*)Bt + (long)(n0 + cch * 32 + srow) * 1024 + k0 + scol),
                (__attribute__((address_space(3))) void*)(&Bs[buf][ldsOff + cch * 32 * 64]), 16, 0, 0);
        }
    };

    issue(0, 0);
#pragma unroll
    for (int t = 0; t < 16; t++) {
        const int cur = t & 1;
        __syncthreads();                  // drains DMA(t); all waves' reads of this buf (from t-2) are done
        if (t < 15) issue(t + 1, cur ^ 1);
#pragma unroll
        for (int ks = 0; ks < 2; ks++) {
            frag8 af[4], bf[4];
#pragma unroll
            for (int i = 0; i < 4; i++)
                af[i] = *(const frag8*)(&As[cur][(wm + i * 16 + fr) * 64 + (((ks * 4 + fq) ^ sw) * 8)]);
#pragma unroll
            for (int j = 0; j < 4; j++)
                bf[j] = *(const frag8*)(&Bs[cur][(wn + j * 16 + fr) * 64 + (((ks * 4 + fq) ^ sw) * 8)]);
#pragma unroll
            for (int i = 0; i < 4; i++)
#pragma unroll
                for (int j = 0; j < 4; j++)
                    acc[i][j] = __builtin_amdgcn_mfma_f32_16x16x32_bf16(af[i], bf[j], acc[i][j], 0, 0, 0);
        }
    }

    float scj[4], shj[4];
#pragma unroll
    for (int j = 0; j < 4; j++) {
        int col = n0 + wn + j * 16 + fr;
        scj[j] = sc[col]; shj[j] = sh[col];
    }
#pragma unroll
    for (int i = 0; i < 4; i++) {
        int rowb = m0 + wm + i * 16 + fq * 4;
#pragma unroll
        for (int j = 0; j < 4; j++) {
            int col = n0 + wn + j * 16 + fr;
#pragma unroll
            for (int r = 0; r < 4; r++) {
                int row = rowb + r;
                if (row < M) {
                    float y = acc[i][j][r] * scj[j] + shj[j];
                    if constexpr (MODE == 0) {
                        y = fmaxf(y, 0.f);
                        hout[(long)row * 512 + col] = f2bf(y);
                    } else {
                        fout[(long)row * NOUT + col] = y;
                    }
                }
            }
        }
    }
}

extern "C" void kernel_launch(void* const* d_in, const int* in_sizes, int n_in,
                              void* d_out, int out_size, void* d_ws, size_t ws_size,
                              hipStream_t stream) {
    const float* x    = (const float*)d_in[0];
    const int*   ei   = (const int*)d_in[1];
    const float* w_l1 = (const float*)d_in[2];
    const float* b1   = (const float*)d_in[3];
    const float* w_r1 = (const float*)d_in[4];
    const float* g1   = (const float*)d_in[5];
    const float* be1  = (const float*)d_in[6];
    const float* m1   = (const float*)d_in[7];
    const float* v1   = (const float*)d_in[8];
    const float* w_l2 = (const float*)d_in[9];
    const float* b2   = (const float*)d_in[10];
    const float* w_r2 = (const float*)d_in[11];
    const float* g2   = (const float*)d_in[12];
    const float* be2  = (const float*)d_in[13];
    const float* m2   = (const float*)d_in[14];
    const float* v2   = (const float*)d_in[15];
    const float* w_l3 = (const float*)d_in[16];
    const float* b3   = (const float*)d_in[17];
    const float* w_r3 = (const float*)d_in[18];
    float* out = (float*)d_out;

    const int N = NNODE, E = NEDGE;
    const int* srcI = ei;
    const int* dstI = ei + E;

    char* w = (char*)d_ws;
    auto alloc = [&](size_t bytes) { void* p = (void*)w; w += (bytes + 255) & ~(size_t)255; return p; };
    int* deg = (int*)alloc((size_t)N * 4);
    int* rs  = (int*)alloc((size_t)(N + 1) * 4);
    int* cur = (int*)alloc((size_t)N * 4);
    int* csr = (int*)alloc((size_t)E * 4);
    unsigned short* xb   = (unsigned short*)alloc((size_t)N * 512 * 2);
    unsigned short* bt1  = (unsigned short*)alloc((size_t)512 * 1024 * 2);
    unsigned short* bt2  = (unsigned short*)alloc((size_t)512 * 1024 * 2);
    unsigned short* bt3  = (unsigned short*)alloc((size_t)256 * 1024 * 2);
    float* sc1 = (float*)alloc(512 * 4); float* sh1 = (float*)alloc(512 * 4);
    float* sc2 = (float*)alloc(512 * 4); float* sh2 = (float*)alloc(512 * 4);
    float* sc3 = (float*)alloc(256 * 4); float* sh3 = (float*)alloc(256 * 4);
    unsigned short* agg_a = (unsigned short*)alloc((size_t)N * 512 * 2);
    unsigned short* h1    = (unsigned short*)alloc((size_t)N * 512 * 2);
    unsigned short* h2    = (unsigned short*)alloc((size_t)N * 512 * 2);
    (void)alloc(256 * 1024);  // DMA over-read slack for last M-tile

    hipMemsetAsync(deg, 0, (size_t)N * 4, stream);
    k_prep<<<6906, 256, 0, stream>>>(x, xb, w_l1, w_r1, w_l2, w_r2, w_l3, w_r3,
                                     bt1, bt2, bt3,
                                     b1, g1, be1, m1, v1, b2, g2, be2, m2, v2, b3,
                                     sc1, sh1, sc2, sh2, sc3, sh3, dstI, deg);
    k_scan<<<1, 1024, 0, stream>>>(deg, rs, cur, N, E);
    k_fill<<<(E + 255) / 256, 256, 0, stream>>>(srcI, dstI, E, cur, csr);

    dim3 ga(N, 2);

    // grids: ceil(79/8)=10 strip-groups * 8 XCD * NT n-tiles
    // Layer 1
    k_agg<<<ga, 64, 0, stream>>>(xb, rs, csr, agg_a);
    k_gemm<0, 512><<<320, 256, 0, stream>>>(agg_a, xb, bt1, sc1, sh1, h1, nullptr, N);
    // Layer 2
    k_agg<<<ga, 64, 0, stream>>>(h1, rs, csr, agg_a);
    k_gemm<0, 512><<<320, 256, 0, stream>>>(agg_a, h1, bt2, sc2, sh2, h2, nullptr, N);
    // Layer 3
    k_agg<<<ga, 64, 0, stream>>>(h2, rs, csr, agg_a);
    k_gemm<1, 256><<<160, 256, 0, stream>>>(agg_a, h2, bt3, sc3, sh3, nullptr, out, N);
}